// Round 1
// baseline (919.382 us; speedup 1.0000x reference)
//
#include <hip/hip_runtime.h>

#define BATCH 32
#define CIN_  64
#define COUT_ 64
#define H_    224
#define W_    224
#define HW_   (H_*W_)

#define HT     2            // output rows per block
#define WTILE  112          // output cols per block
#define XS_P   116          // padded pixels per LDS row (need 114)
#define NROWS  (HT+2)
#define NTILES (WTILE/16)   // 7

typedef __bf16 bf16x4 __attribute__((ext_vector_type(4)));
typedef __bf16 bf16x8 __attribute__((ext_vector_type(8)));
typedef float  f32x4  __attribute__((ext_vector_type(4)));

// Binarize weights: wp[tap][co][ci] = bf16(sign(w[co][ci][tap]))
__global__ void bc_prep(const float* __restrict__ w, __bf16* __restrict__ wp) {
    int gid = blockIdx.x * 256 + threadIdx.x;
    if (gid >= COUT_ * CIN_ * 9) return;
    int co  = gid / (CIN_ * 9);
    int rem = gid - co * (CIN_ * 9);
    int ci  = rem / 9;
    int t   = rem - ci * 9;
    float v = w[gid];
    float s = (v > 0.0f) ? 1.0f : ((v < 0.0f) ? -1.0f : 0.0f);
    wp[t * (COUT_ * CIN_) + co * CIN_ + ci] = (__bf16)s;
}

// Implicit-GEMM binary conv. Block: (b, h-tile of 2, w-tile of 112), all 64 co.
// Wave = one 16-co tile; 18 A-frags (weights) live in VGPRs.
// LDS x-tile layout: xs[row][px][ci] bf16, ci-chunk XOR-swizzled so that
// both ds_write_b64 staging and ds_read_b128 B-frag loads are ~conflict-free.
__global__ __launch_bounds__(256, 2)
void bc_main(const float* __restrict__ x, const __bf16* __restrict__ wp,
             const float* __restrict__ bias, float* __restrict__ out) {
    __shared__ __attribute__((aligned(16))) __bf16 xs[NROWS * XS_P * 64];

    const int htile = blockIdx.x;     // 0..111
    const int wt    = blockIdx.y;     // 0..1
    const int b     = blockIdx.z;     // 0..31
    const int h0 = htile * HT;
    const int w0 = wt * WTILE;

    const int tid  = threadIdx.x;
    const int lane = tid & 63;
    const int wave = tid >> 6;        // co-tile index 0..3
    const int col  = lane & 15;
    const int quad = lane >> 4;

    // ---- A fragments: A[m=lane&15][k=quad*8+j], k = tap*64 + ci ----
    bf16x8 afrag[18];
    {
        const int m = wave * 16 + col;
        #pragma unroll
        for (int kc = 0; kc < 18; ++kc) {
            const int tap = kc >> 1;
            const int cib = (kc & 1) * 32 + quad * 8;
            afrag[kc] = *(const bf16x8*)(wp + tap * (COUT_ * CIN_) + m * CIN_ + cib);
        }
    }
    float biasr[4];
    #pragma unroll
    for (int r = 0; r < 4; ++r) biasr[r] = bias[wave * 16 + quad * 4 + r];

    // ---- stage input tile: transpose NCHW -> xs[row][px][ci] (bf16) ----
    // xs px p corresponds to input w = w0 - 1 + p.
    const int cig   = tid >> 4;        // 0..15 : 4-ci group (4 per wave)
    const int ci0   = cig * 4;
    const int cc    = cig >> 1;        // 8-ci chunk index 0..7
    const int chalf = (cig & 1) * 4;   // offset inside chunk

    #pragma unroll
    for (int r = 0; r < NROWS; ++r) {
        const int hin = h0 - 1 + r;
        const bool rowok = (hin >= 0) && (hin < H_);
        const float* src = x + (size_t)b * CIN_ * HW_ + (size_t)hin * W_;
        #pragma unroll
        for (int s = 0; s < 2; ++s) {
            const int pxg = (tid & 15) + s * 16;   // 0..31
            const int wbase = w0 - 4 + pxg * 4;    // aligned global w of elem 0
            float vv[4][4];
            #pragma unroll
            for (int j = 0; j < 4; ++j) {
                const float* pr = src + (size_t)(ci0 + j) * HW_ + wbase;
                if (rowok && wbase >= 0 && wbase + 3 < W_) {
                    float4 f = *(const float4*)pr;
                    vv[j][0] = f.x; vv[j][1] = f.y; vv[j][2] = f.z; vv[j][3] = f.w;
                } else {
                    #pragma unroll
                    for (int i = 0; i < 4; ++i) {
                        const int wg = wbase + i;
                        vv[j][i] = (rowok && wg >= 0 && wg < W_) ? pr[i] : 0.0f;
                    }
                }
            }
            #pragma unroll
            for (int i = 0; i < 4; ++i) {
                const int p = pxg * 4 + i - 3;     // xs pixel index
                if (p >= 0 && p < XS_P) {
                    bf16x4 pk;
                    pk[0] = (__bf16)vv[0][i];
                    pk[1] = (__bf16)vv[1][i];
                    pk[2] = (__bf16)vv[2][i];
                    pk[3] = (__bf16)vv[3][i];
                    const int cp = cc ^ ((p >> 1) & 7);
                    *(bf16x4*)&xs[(r * XS_P + p) * 64 + cp * 8 + chalf] = pk;
                }
            }
        }
    }
    __syncthreads();

    // ---- main MFMA loops ----
    #pragma unroll
    for (int hh = 0; hh < HT; ++hh) {
        for (int nt = 0; nt < NTILES; ++nt) {
            const int pw = nt * 16;
            const int pc = pw + col;               // lane's pixel base
            f32x4 acc = (f32x4){0.f, 0.f, 0.f, 0.f};
            #pragma unroll
            for (int kc = 0; kc < 18; ++kc) {
                const int tap = kc >> 1;
                const int dh  = tap / 3;
                const int dw  = tap - dh * 3;
                const int pin = pc + dw;           // xs pixel for this tap
                const int c   = (kc & 1) * 4 + quad;
                const int cp  = c ^ ((pin >> 1) & 7);
                const bf16x8* bsrc =
                    (const bf16x8*)&xs[((hh + dh) * XS_P + pin) * 64 + cp * 8];
                acc = __builtin_amdgcn_mfma_f32_16x16x32_bf16(afrag[kc], *bsrc, acc, 0, 0, 0);
            }
            // D: row = co_local = quad*4+r, col = pixel
            float* op = out + (((size_t)b * COUT_ + wave * 16 + quad * 4) * H_ + (h0 + hh)) * W_
                            + (w0 + pw + col);
            #pragma unroll
            for (int r = 0; r < 4; ++r)
                op[(size_t)r * HW_] = acc[r] + biasr[r];
        }
    }
}

extern "C" void kernel_launch(void* const* d_in, const int* in_sizes, int n_in,
                              void* d_out, int out_size, void* d_ws, size_t ws_size,
                              hipStream_t stream) {
    const float* x    = (const float*)d_in[0];
    const float* w    = (const float*)d_in[1];
    const float* bias = (const float*)d_in[2];
    float* out = (float*)d_out;
    __bf16* wp = (__bf16*)d_ws;   // 9*64*64*2 = 73728 B

    bc_prep<<<dim3((COUT_ * CIN_ * 9 + 255) / 256), dim3(256), 0, stream>>>(w, wp);
    bc_main<<<dim3(H_ / HT, W_ / WTILE, BATCH), dim3(256), 0, stream>>>(x, wp, bias, out);
}